// Round 1
// baseline (375.638 us; speedup 1.0000x reference)
//
#include <hip/hip_runtime.h>
#include <math.h>

#define DM 256
#define SQ 4096
#define BT 2
#define NS 16
#define NTOK (BT*SQ)
#define NCHK 64
#define CHL (SQ/NCHK)

__device__ __forceinline__ float sigm_(float x){ return 1.f/(1.f+__expf(-x)); }
__device__ __forceinline__ float silu_(float x){ return x*sigm_(x); }
__device__ __forceinline__ float softplus_(float x){ return (x>20.f)? x : log1pf(__expf(x)); }

// ---------- LN stats over input rows (one wave per token) ----------
__global__ __launch_bounds__(256) void k_stats_in(const float* __restrict__ x,
                                                  float* __restrict__ mean, float* __restrict__ rstd){
  int tok = blockIdx.x*4 + (threadIdx.x>>6);
  int lane = threadIdx.x & 63;
  const float* row = x + (size_t)tok*DM;
  float s=0.f, ss=0.f;
  #pragma unroll
  for (int j=0;j<4;j++){ float v=row[lane + 64*j]; s+=v; ss+=v*v; }
  #pragma unroll
  for (int o=32;o>0;o>>=1){ s += __shfl_xor(s,o,64); ss += __shfl_xor(ss,o,64); }
  if (lane==0){ float m=s*(1.f/DM); float v=ss*(1.f/DM)-m*m; mean[tok]=m; rstd[tok]=rsqrtf(v+1e-5f); }
}

__global__ __launch_bounds__(256) void k_stats_y(const float* __restrict__ yf, const float* __restrict__ yb,
                                                 float* __restrict__ mean, float* __restrict__ rstd){
  int tok = blockIdx.x*4 + (threadIdx.x>>6);
  int lane = threadIdx.x & 63;
  size_t base = (size_t)tok*DM;
  float s=0.f, ss=0.f;
  #pragma unroll
  for (int j=0;j<4;j++){ int c=lane+64*j; float v=0.5f*(yf[base+c]+yb[base+c]); s+=v; ss+=v*v; }
  #pragma unroll
  for (int o=32;o>0;o>>=1){ s += __shfl_xor(s,o,64); ss += __shfl_xor(ss,o,64); }
  if (lane==0){ float m=s*(1.f/DM); float v=ss*(1.f/DM)-m*m; mean[tok]=m; rstd[tok]=rsqrtf(v+1e-5f); }
}

// ---------- fused LN + in_proj GEMM: xz[tok][o] = sum_k LN(x)[tok][k]*W[o][k] ----------
// tile: 64 tokens x 64 outputs, kc=16, 256 threads, 4x4 acc/thread
__global__ __launch_bounds__(256) void k_inproj(
    const float* __restrict__ x, const float* __restrict__ mean, const float* __restrict__ rstd,
    const float* __restrict__ g, const float* __restrict__ nb,
    const float* __restrict__ W, float* __restrict__ xin, float* __restrict__ z)
{
  __shared__ float As[64*17];
  __shared__ float Ws[64*17];
  int tid = threadIdx.x;
  int tt = blockIdx.x, ot = blockIdx.y;
  int tx = tid & 15, ty = tid >> 4;
  int li = tid >> 2, lk = (tid & 3)*4;
  int tok = tt*64 + li;
  float m = mean[tok], r = rstd[tok];
  float acc[4][4] = {};
  for (int k0=0;k0<DM;k0+=16){
    float4 v  = *(const float4*)(x + (size_t)tok*DM + k0 + lk);
    float4 gv = *(const float4*)(g + k0 + lk);
    float4 bv = *(const float4*)(nb + k0 + lk);
    As[li*17+lk+0] = (v.x-m)*r*gv.x+bv.x;
    As[li*17+lk+1] = (v.y-m)*r*gv.y+bv.y;
    As[li*17+lk+2] = (v.z-m)*r*gv.z+bv.z;
    As[li*17+lk+3] = (v.w-m)*r*gv.w+bv.w;
    float4 w4 = *(const float4*)(W + (size_t)(ot*64+li)*DM + k0 + lk);
    Ws[li*17+lk+0]=w4.x; Ws[li*17+lk+1]=w4.y; Ws[li*17+lk+2]=w4.z; Ws[li*17+lk+3]=w4.w;
    __syncthreads();
    #pragma unroll
    for (int k=0;k<16;k++){
      float a0=As[(ty*4+0)*17+k], a1=As[(ty*4+1)*17+k], a2=As[(ty*4+2)*17+k], a3=As[(ty*4+3)*17+k];
      float w0=Ws[(tx*4+0)*17+k], w1=Ws[(tx*4+1)*17+k], w2=Ws[(tx*4+2)*17+k], w3=Ws[(tx*4+3)*17+k];
      acc[0][0]+=a0*w0; acc[0][1]+=a0*w1; acc[0][2]+=a0*w2; acc[0][3]+=a0*w3;
      acc[1][0]+=a1*w0; acc[1][1]+=a1*w1; acc[1][2]+=a1*w2; acc[1][3]+=a1*w3;
      acc[2][0]+=a2*w0; acc[2][1]+=a2*w1; acc[2][2]+=a2*w2; acc[2][3]+=a2*w3;
      acc[3][0]+=a3*w0; acc[3][1]+=a3*w1; acc[3][2]+=a3*w2; acc[3][3]+=a3*w3;
    }
    __syncthreads();
  }
  #pragma unroll
  for (int q=0;q<4;q++){
    int tq = tt*64 + ty*4 + q;
    #pragma unroll
    for (int p=0;p<4;p++){
      int o = ot*64 + tx*4 + p;
      float vv = acc[q][p];
      if (o < DM) xin[(size_t)tq*DM + o] = vv;
      else        z  [(size_t)tq*DM + (o-DM)] = vv;
    }
  }
}

// ---------- causal depthwise conv (K=4) + silu, fwd and time-reversed bwd ----------
__global__ __launch_bounds__(256) void k_conv(
    const float* __restrict__ xin,
    const float* __restrict__ cw_f, const float* __restrict__ cb_f,
    const float* __restrict__ cw_b, const float* __restrict__ cb_b,
    float* __restrict__ uf, float* __restrict__ ub)
{
  int d = threadIdx.x;
  int b = blockIdx.y;
  int dir = blockIdx.z;
  int t0 = blockIdx.x*16;
  const float* w  = dir? cw_b : cw_f;
  const float* bi = dir? cb_b : cb_f;
  float w0=w[d*4], w1=w[d*4+1], w2=w[d*4+2], w3=w[d*4+3];
  float bb = bi[d];
  float* out = dir? ub : uf;
  for (int i=0;i<16;i++){
    int t = t0+i;
    float acc = bb;
    #pragma unroll
    for (int k=0;k<4;k++){
      int tt = t-3+k;
      if (tt>=0){
        int src = dir? (SQ-1-tt) : tt;
        float wk = (k==0)?w0:(k==1)?w1:(k==2)?w2:w3;
        acc += wk * xin[((size_t)b*SQ+src)*DM + d];
      }
    }
    out[((size_t)b*SQ+t)*DM + d] = silu_(acc);
  }
}

// ---------- xproj (48 dots of 256) + dtproj (16->256) + softplus, per token ----------
__global__ __launch_bounds__(256) void k_xproj(
    const float* __restrict__ uf, const float* __restrict__ ub,
    const float* __restrict__ xw_f, const float* __restrict__ xw_b,
    const float* __restrict__ dtw_f, const float* __restrict__ dtw_b,
    const float* __restrict__ dtbias_f, const float* __restrict__ dtbias_b,
    float* __restrict__ dtf, float* __restrict__ dtb,
    float* __restrict__ bmf, float* __restrict__ cmf,
    float* __restrict__ bmb, float* __restrict__ cmb)
{
  int tau = blockIdx.x;
  int dir = blockIdx.y;
  const float* u   = dir? ub : uf;
  const float* xw  = dir? xw_b : xw_f;
  const float* dtw = dir? dtw_b : dtw_f;
  const float* dbi = dir? dtbias_b : dtbias_f;
  float* dt = dir? dtb : dtf;
  float* bm = dir? bmb : bmf;
  float* cm = dir? cmb : cmf;
  __shared__ float su[256];
  __shared__ float sd[48];
  int tid = threadIdx.x;
  su[tid] = u[(size_t)tau*DM + tid];
  __syncthreads();
  if (tid < 48){
    float acc = 0.f;
    const float* wr = xw + tid*DM;
    for (int k=0;k<DM;k++) acc += su[k]*wr[k];
    sd[tid] = acc;
  }
  __syncthreads();
  float acc = dbi[tid];
  const float* wr = dtw + tid*NS;
  #pragma unroll
  for (int r=0;r<NS;r++) acc += sd[r]*wr[r];
  dt[(size_t)tau*DM + tid] = softplus_(acc);
  if (tid < NS){ bm[(size_t)tau*NS+tid] = sd[16+tid]; cm[(size_t)tau*NS+tid] = sd[32+tid]; }
}

// ---------- scan phase 1: per-chunk summaries (Aprod, h_end) ----------
__global__ __launch_bounds__(256) void k_scan1(
    const float* __restrict__ dtf, const float* __restrict__ dtb,
    const float* __restrict__ uf, const float* __restrict__ ub,
    const float* __restrict__ bmf, const float* __restrict__ bmb,
    const float* __restrict__ alog_f, const float* __restrict__ alog_b,
    float* __restrict__ apf, float* __restrict__ hsf,
    float* __restrict__ apb, float* __restrict__ hsb)
{
  int c = blockIdx.x, b = blockIdx.y, dir = blockIdx.z;
  const float* dt = dir? dtb : dtf;
  const float* u  = dir? ub  : uf;
  const float* bmp= dir? bmb : bmf;
  const float* al = dir? alog_b : alog_f;
  float* ap = dir? apb : apf;
  float* hs = dir? hsb : hsf;
  int d = threadIdx.x;
  __shared__ float sB[CHL*NS];
  for (int i=threadIdx.x;i<CHL*NS;i+=256) sB[i] = bmp[((size_t)b*SQ + c*CHL)*NS + i];
  float A[NS];
  #pragma unroll
  for (int n=0;n<NS;n++) A[n] = -__expf(al[d*NS+n]);
  float h[NS] = {};
  float dts = 0.f;
  __syncthreads();
  for (int t=0;t<CHL;t++){
    size_t idx = ((size_t)b*SQ + c*CHL + t)*DM + d;
    float dtv = dt[idx];
    float uv  = u[idx];
    float du  = dtv*uv;
    dts += dtv;
    #pragma unroll
    for (int n=0;n<NS;n++) h[n] = h[n]*__expf(dtv*A[n]) + du*sB[t*NS+n];
  }
  size_t o = (((size_t)b*NCHK + c)*DM + d)*NS;
  #pragma unroll
  for (int n=0;n<NS;n++){ hs[o+n] = h[n]; ap[o+n] = __expf(A[n]*dts); }
}

// ---------- scan phase 2: sequential scan over chunk summaries (in place -> prefixes) ----------
__global__ __launch_bounds__(256) void k_scan2(
    float* __restrict__ apf, float* __restrict__ hsf,
    float* __restrict__ apb, float* __restrict__ hsb)
{
  int gid = blockIdx.x*256 + threadIdx.x;     // 0..16383
  int dir = gid >> 13;
  int rem = gid & 8191;
  int b   = rem >> 12;
  int dn  = rem & 4095;
  const float* ap = dir? apb : apf;
  float* hs = dir? hsb : hsf;
  float h = 0.f;
  for (int c=0;c<NCHK;c++){
    size_t idx = ((size_t)b*NCHK + c)*4096 + dn;
    float a = ap[idx];
    float v = hs[idx];
    hs[idx] = h;          // prefix (state entering chunk c)
    h = h*a + v;
  }
}

// ---------- scan phase 3: replay with prefix, emit y ----------
__global__ __launch_bounds__(256) void k_scan3(
    const float* __restrict__ dt, const float* __restrict__ u,
    const float* __restrict__ bmp, const float* __restrict__ cmp,
    const float* __restrict__ al, const float* __restrict__ Dv,
    const float* __restrict__ z, const float* __restrict__ hs,
    float* __restrict__ yout, int dir)
{
  int c = blockIdx.x, b = blockIdx.y;
  int d = threadIdx.x;
  __shared__ float sB[CHL*NS];
  __shared__ float sC[CHL*NS];
  for (int i=threadIdx.x;i<CHL*NS;i+=256){
    sB[i] = bmp[((size_t)b*SQ + c*CHL)*NS + i];
    sC[i] = cmp[((size_t)b*SQ + c*CHL)*NS + i];
  }
  float A[NS], h[NS];
  size_t o = (((size_t)b*NCHK + c)*DM + d)*NS;
  #pragma unroll
  for (int n=0;n<NS;n++){ A[n] = -__expf(al[d*NS+n]); h[n] = hs[o+n]; }
  float Dd = Dv[d];
  __syncthreads();
  for (int t=0;t<CHL;t++){
    int gt = c*CHL + t;
    size_t idx = ((size_t)b*SQ + gt)*DM + d;
    float dtv = dt[idx];
    float uv  = u[idx];
    float du  = dtv*uv;
    float y = 0.f;
    #pragma unroll
    for (int n=0;n<NS;n++){
      h[n] = h[n]*__expf(dtv*A[n]) + du*sB[t*NS+n];
      y += h[n]*sC[t*NS+n];
    }
    y += uv*Dd;
    int torig = dir ? (SQ-1-gt) : gt;
    size_t oidx = ((size_t)b*SQ + torig)*DM + d;
    float zv = z[oidx];
    yout[oidx] = y * (zv * sigm_(zv));
  }
}

// ---------- final: LN(y) @ out_proj.T -> LN -> + skip ----------
__global__ __launch_bounds__(256) void k_final(
    const float* __restrict__ yf, const float* __restrict__ yb,
    const float* __restrict__ meanY, const float* __restrict__ rstdY,
    const float* __restrict__ og, const float* __restrict__ ob,
    const float* __restrict__ Wout,
    const float* __restrict__ pg, const float* __restrict__ pb,
    const float* __restrict__ skip, float* __restrict__ out)
{
  __shared__ float Yn[16*16];
  __shared__ float Ws[256*17];
  __shared__ float sOut[16*256];
  __shared__ float sm[16], sr[16];
  int tt = blockIdx.x;
  int tid = threadIdx.x;
  float acc[16] = {};
  int i = tid>>4, kk = tid&15;
  int tok_i = tt*16 + i;
  float mI = meanY[tok_i], rI = rstdY[tok_i];
  for (int k0=0;k0<DM;k0+=16){
    float v = 0.5f*(yf[(size_t)tok_i*DM+k0+kk] + yb[(size_t)tok_i*DM+k0+kk]);
    Yn[i*16+kk] = (v - mI)*rI*og[k0+kk] + ob[k0+kk];
    const float* wr = Wout + (size_t)tid*DM + k0;
    #pragma unroll
    for (int e=0;e<16;e++) Ws[tid*17+e] = wr[e];
    __syncthreads();
    #pragma unroll
    for (int k2=0;k2<16;k2++){
      float w = Ws[tid*17+k2];
      #pragma unroll
      for (int t=0;t<16;t++) acc[t] += Yn[t*16+k2]*w;
    }
    __syncthreads();
  }
  #pragma unroll
  for (int t=0;t<16;t++) sOut[t*256+tid] = acc[t];
  __syncthreads();
  int wv = tid>>6, lane = tid&63;
  for (int j=0;j<4;j++){
    int t = wv*4+j;
    float s=0.f, ss=0.f;
    #pragma unroll
    for (int q=0;q<4;q++){ float v=sOut[t*256+lane+64*q]; s+=v; ss+=v*v; }
    #pragma unroll
    for (int o=32;o>0;o>>=1){ s += __shfl_xor(s,o,64); ss += __shfl_xor(ss,o,64); }
    if (lane==0){ float m=s*(1.f/DM); sm[t]=m; sr[t]=rsqrtf(ss*(1.f/DM)-m*m+1e-5f); }
  }
  __syncthreads();
  float gv = pg[tid], bv = pb[tid];
  for (int t=0;t<16;t++){
    int tok = tt*16+t;
    float v = (sOut[t*256+tid]-sm[t])*sr[t]*gv + bv + skip[(size_t)tok*DM+tid];
    out[(size_t)tok*DM+tid] = v;
  }
}

extern "C" void kernel_launch(void* const* d_in, const int* in_sizes, int n_in,
                              void* d_out, int out_size, void* d_ws, size_t ws_size,
                              hipStream_t stream)
{
  const float* input      = (const float*)d_in[0];
  const float* norm_g     = (const float*)d_in[1];
  const float* norm_b     = (const float*)d_in[2];
  const float* in_proj_w  = (const float*)d_in[3];
  const float* conv_w     = (const float*)d_in[4];
  const float* conv_b     = (const float*)d_in[5];
  const float* xproj_w    = (const float*)d_in[6];
  const float* dtproj_w   = (const float*)d_in[7];
  const float* dtproj_b   = (const float*)d_in[8];
  const float* A_log      = (const float*)d_in[9];
  const float* Dp         = (const float*)d_in[10];
  const float* conv_w_b   = (const float*)d_in[11];
  const float* conv_b_b   = (const float*)d_in[12];
  const float* xproj_w_b  = (const float*)d_in[13];
  const float* dtproj_w_b = (const float*)d_in[14];
  const float* dtproj_b_b = (const float*)d_in[15];
  const float* A_log_b    = (const float*)d_in[16];
  const float* Dp_b       = (const float*)d_in[17];
  const float* out_norm_g = (const float*)d_in[18];
  const float* out_norm_b = (const float*)d_in[19];
  const float* out_proj_w = (const float*)d_in[20];
  const float* post_norm_g= (const float*)d_in[21];
  const float* post_norm_b= (const float*)d_in[22];
  float* out = (float*)d_out;

  float* ws = (float*)d_ws;
  const size_t M2 = (size_t)NTOK*DM;       // 2M floats
  float* xin = ws;                // later reused as y_f
  float* z   = ws + M2;
  float* uf  = ws + 2*M2;         // later reused as y_b
  float* ub  = ws + 3*M2;
  float* dtf = ws + 4*M2;
  float* dtb = ws + 5*M2;
  float* p   = ws + 6*M2;
  float* bmf = p;              p += (size_t)NTOK*NS;
  float* cmf = p;              p += (size_t)NTOK*NS;
  float* bmb = p;              p += (size_t)NTOK*NS;
  float* cmb = p;              p += (size_t)NTOK*NS;
  float* apf = p;              p += (size_t)BT*NCHK*DM*NS;
  float* hsf = p;              p += (size_t)BT*NCHK*DM*NS;
  float* apb = p;              p += (size_t)BT*NCHK*DM*NS;
  float* hsb = p;              p += (size_t)BT*NCHK*DM*NS;
  float* meanX = p;            p += NTOK;
  float* rstdX = p;            p += NTOK;
  float* meanY = p;            p += NTOK;
  float* rstdY = p;            p += NTOK;
  float* yf = xin;
  float* yb = uf;

  k_stats_in<<<NTOK/4, 256, 0, stream>>>(input, meanX, rstdX);
  k_inproj<<<dim3(NTOK/64, 8, 1), 256, 0, stream>>>(input, meanX, rstdX, norm_g, norm_b,
                                                    in_proj_w, xin, z);
  k_conv<<<dim3(SQ/16, BT, 2), 256, 0, stream>>>(xin, conv_w, conv_b, conv_w_b, conv_b_b, uf, ub);
  k_xproj<<<dim3(NTOK, 2, 1), 256, 0, stream>>>(uf, ub, xproj_w, xproj_w_b,
                                                dtproj_w, dtproj_w_b, dtproj_b, dtproj_b_b,
                                                dtf, dtb, bmf, cmf, bmb, cmb);
  k_scan1<<<dim3(NCHK, BT, 2), 256, 0, stream>>>(dtf, dtb, uf, ub, bmf, bmb, A_log, A_log_b,
                                                 apf, hsf, apb, hsb);
  k_scan2<<<64, 256, 0, stream>>>(apf, hsf, apb, hsb);
  // fwd writes y_f into xin (xin dead); bwd writes y_b into uf (uf dead after fwd) -> ordered launches
  k_scan3<<<dim3(NCHK, BT, 1), 256, 0, stream>>>(dtf, uf, bmf, cmf, A_log, Dp, z, hsf, yf, 0);
  k_scan3<<<dim3(NCHK, BT, 1), 256, 0, stream>>>(dtb, ub, bmb, cmb, A_log_b, Dp_b, z, hsb, yb, 1);
  k_stats_y<<<NTOK/4, 256, 0, stream>>>(yf, yb, meanY, rstdY);
  k_final<<<NTOK/16, 256, 0, stream>>>(yf, yb, meanY, rstdY, out_norm_g, out_norm_b,
                                       out_proj_w, post_norm_g, post_norm_b, input, out);
}

// Round 2
// 311.284 us; speedup vs baseline: 1.2067x; 1.2067x over previous
//
#include <hip/hip_runtime.h>
#include <math.h>

#define DM 256
#define SQ 4096
#define BT 2
#define NS 16
#define NTOK (BT*SQ)
#define NCHK 64
#define CHL (SQ/NCHK)

__device__ __forceinline__ float sigm_(float x){ return 1.f/(1.f+__expf(-x)); }
__device__ __forceinline__ float silu_(float x){ return x*sigm_(x); }
__device__ __forceinline__ float softplus_(float x){ return (x>20.f)? x : log1pf(__expf(x)); }

// ---------- LN stats over input rows (one wave per token) ----------
__global__ __launch_bounds__(256) void k_stats_in(const float* __restrict__ x,
                                                  float* __restrict__ mean, float* __restrict__ rstd){
  int tok = blockIdx.x*4 + (threadIdx.x>>6);
  int lane = threadIdx.x & 63;
  const float* row = x + (size_t)tok*DM;
  float s=0.f, ss=0.f;
  #pragma unroll
  for (int j=0;j<4;j++){ float v=row[lane + 64*j]; s+=v; ss+=v*v; }
  #pragma unroll
  for (int o=32;o>0;o>>=1){ s += __shfl_xor(s,o,64); ss += __shfl_xor(ss,o,64); }
  if (lane==0){ float m=s*(1.f/DM); float v=ss*(1.f/DM)-m*m; mean[tok]=m; rstd[tok]=rsqrtf(v+1e-5f); }
}

__global__ __launch_bounds__(256) void k_stats_y(const float* __restrict__ yf, const float* __restrict__ yb,
                                                 float* __restrict__ mean, float* __restrict__ rstd){
  int tok = blockIdx.x*4 + (threadIdx.x>>6);
  int lane = threadIdx.x & 63;
  size_t base = (size_t)tok*DM;
  float s=0.f, ss=0.f;
  #pragma unroll
  for (int j=0;j<4;j++){ int c=lane+64*j; float v=0.5f*(yf[base+c]+yb[base+c]); s+=v; ss+=v*v; }
  #pragma unroll
  for (int o=32;o>0;o>>=1){ s += __shfl_xor(s,o,64); ss += __shfl_xor(ss,o,64); }
  if (lane==0){ float m=s*(1.f/DM); float v=ss*(1.f/DM)-m*m; mean[tok]=m; rstd[tok]=rsqrtf(v+1e-5f); }
}

// ---------- fused LN + in_proj GEMM: xz[tok][o] = sum_k LN(x)[tok][k]*W[o][k] ----------
__global__ __launch_bounds__(256) void k_inproj(
    const float* __restrict__ x, const float* __restrict__ mean, const float* __restrict__ rstd,
    const float* __restrict__ g, const float* __restrict__ nb,
    const float* __restrict__ W, float* __restrict__ xin, float* __restrict__ z)
{
  __shared__ float As[64*17];
  __shared__ float Ws[64*17];
  int tid = threadIdx.x;
  int tt = blockIdx.x, ot = blockIdx.y;
  int tx = tid & 15, ty = tid >> 4;
  int li = tid >> 2, lk = (tid & 3)*4;
  int tok = tt*64 + li;
  float m = mean[tok], r = rstd[tok];
  float acc[4][4] = {};
  for (int k0=0;k0<DM;k0+=16){
    float4 v  = *(const float4*)(x + (size_t)tok*DM + k0 + lk);
    float4 gv = *(const float4*)(g + k0 + lk);
    float4 bv = *(const float4*)(nb + k0 + lk);
    As[li*17+lk+0] = (v.x-m)*r*gv.x+bv.x;
    As[li*17+lk+1] = (v.y-m)*r*gv.y+bv.y;
    As[li*17+lk+2] = (v.z-m)*r*gv.z+bv.z;
    As[li*17+lk+3] = (v.w-m)*r*gv.w+bv.w;
    float4 w4 = *(const float4*)(W + (size_t)(ot*64+li)*DM + k0 + lk);
    Ws[li*17+lk+0]=w4.x; Ws[li*17+lk+1]=w4.y; Ws[li*17+lk+2]=w4.z; Ws[li*17+lk+3]=w4.w;
    __syncthreads();
    #pragma unroll
    for (int k=0;k<16;k++){
      float a0=As[(ty*4+0)*17+k], a1=As[(ty*4+1)*17+k], a2=As[(ty*4+2)*17+k], a3=As[(ty*4+3)*17+k];
      float w0=Ws[(tx*4+0)*17+k], w1=Ws[(tx*4+1)*17+k], w2=Ws[(tx*4+2)*17+k], w3=Ws[(tx*4+3)*17+k];
      acc[0][0]+=a0*w0; acc[0][1]+=a0*w1; acc[0][2]+=a0*w2; acc[0][3]+=a0*w3;
      acc[1][0]+=a1*w0; acc[1][1]+=a1*w1; acc[1][2]+=a1*w2; acc[1][3]+=a1*w3;
      acc[2][0]+=a2*w0; acc[2][1]+=a2*w1; acc[2][2]+=a2*w2; acc[2][3]+=a2*w3;
      acc[3][0]+=a3*w0; acc[3][1]+=a3*w1; acc[3][2]+=a3*w2; acc[3][3]+=a3*w3;
    }
    __syncthreads();
  }
  #pragma unroll
  for (int q=0;q<4;q++){
    int tq = tt*64 + ty*4 + q;
    #pragma unroll
    for (int p=0;p<4;p++){
      int o = ot*64 + tx*4 + p;
      float vv = acc[q][p];
      if (o < DM) xin[(size_t)tq*DM + o] = vv;
      else        z  [(size_t)tq*DM + (o-DM)] = vv;
    }
  }
}

// ---------- causal depthwise conv (K=4) + silu, fwd and time-reversed bwd ----------
__global__ __launch_bounds__(256) void k_conv(
    const float* __restrict__ xin,
    const float* __restrict__ cw_f, const float* __restrict__ cb_f,
    const float* __restrict__ cw_b, const float* __restrict__ cb_b,
    float* __restrict__ uf, float* __restrict__ ub)
{
  int d = threadIdx.x;
  int b = blockIdx.y;
  int dir = blockIdx.z;
  int t0 = blockIdx.x*16;
  const float* w  = dir? cw_b : cw_f;
  const float* bi = dir? cb_b : cb_f;
  float w0=w[d*4], w1=w[d*4+1], w2=w[d*4+2], w3=w[d*4+3];
  float bb = bi[d];
  float* out = dir? ub : uf;
  for (int i=0;i<16;i++){
    int t = t0+i;
    float acc = bb;
    #pragma unroll
    for (int k=0;k<4;k++){
      int tt = t-3+k;
      if (tt>=0){
        int src = dir? (SQ-1-tt) : tt;
        float wk = (k==0)?w0:(k==1)?w1:(k==2)?w2:w3;
        acc += wk * xin[((size_t)b*SQ+src)*DM + d];
      }
    }
    out[((size_t)b*SQ+t)*DM + d] = silu_(acc);
  }
}

// ---------- xproj GEMM (M=64 tokens/block, N=48, K=256) + fused dtproj + softplus ----------
// outputs: dt (softplus(dbl[:,:16] @ dtw.T + bias)), Bm (dbl[:,16:32]), Cm (dbl[:,32:48])
__global__ __launch_bounds__(256) void k_xproj(
    const float* __restrict__ uf, const float* __restrict__ ub,
    const float* __restrict__ xw_f, const float* __restrict__ xw_b,
    const float* __restrict__ dtw_f, const float* __restrict__ dtw_b,
    const float* __restrict__ dtbias_f, const float* __restrict__ dtbias_b,
    float* __restrict__ dtf, float* __restrict__ dtb,
    float* __restrict__ bmf, float* __restrict__ cmf,
    float* __restrict__ bmb, float* __restrict__ cmb)
{
  int tile = blockIdx.x;          // 0..127, 64 tokens each
  int dir  = blockIdx.y;
  const float* u   = dir? ub : uf;
  const float* xw  = dir? xw_b : xw_f;
  const float* dtw = dir? dtw_b : dtw_f;
  const float* dbi = dir? dtbias_b : dtbias_f;
  float* dt = dir? dtb : dtf;
  float* bm = dir? bmb : bmf;
  float* cm = dir? cmb : cmf;

  __shared__ float As[32][68];    // k-major, token-minor (transposed u tile)
  __shared__ float Ws[48][33];    // (out, k)
  __shared__ float sd[64][20];    // dbl[:, :16] per token

  int tid = threadIdx.x;
  int tx = tid & 15;              // outputs tx*3 .. tx*3+2
  int ty = tid >> 4;              // tokens  ty*4 .. ty*4+3
  int li = tid >> 2;              // 0..63 (token row for loads)
  int lk = (tid & 3) * 8;         // 0,8,16,24

  float acc[4][3] = {};
  for (int k0 = 0; k0 < DM; k0 += 32){
    const float* up = u + (size_t)(tile*64 + li)*DM + k0 + lk;
    float4 a0 = *(const float4*)(up);
    float4 a1 = *(const float4*)(up+4);
    As[lk+0][li]=a0.x; As[lk+1][li]=a0.y; As[lk+2][li]=a0.z; As[lk+3][li]=a0.w;
    As[lk+4][li]=a1.x; As[lk+5][li]=a1.y; As[lk+6][li]=a1.z; As[lk+7][li]=a1.w;
    if (tid < 192){
      int wr = tid >> 2;          // 0..47
      int wk = (tid & 3) * 8;
      const float* wp = xw + (size_t)wr*DM + k0 + wk;
      float4 w0 = *(const float4*)(wp);
      float4 w1 = *(const float4*)(wp+4);
      Ws[wr][wk+0]=w0.x; Ws[wr][wk+1]=w0.y; Ws[wr][wk+2]=w0.z; Ws[wr][wk+3]=w0.w;
      Ws[wr][wk+4]=w1.x; Ws[wr][wk+5]=w1.y; Ws[wr][wk+6]=w1.z; Ws[wr][wk+7]=w1.w;
    }
    __syncthreads();
    #pragma unroll
    for (int k=0;k<32;k++){
      float4 av = *(const float4*)&As[k][ty*4];
      float w0 = Ws[tx*3+0][k], w1 = Ws[tx*3+1][k], w2 = Ws[tx*3+2][k];
      acc[0][0]+=av.x*w0; acc[0][1]+=av.x*w1; acc[0][2]+=av.x*w2;
      acc[1][0]+=av.y*w0; acc[1][1]+=av.y*w1; acc[1][2]+=av.y*w2;
      acc[2][0]+=av.z*w0; acc[2][1]+=av.z*w1; acc[2][2]+=av.z*w2;
      acc[3][0]+=av.w*w0; acc[3][1]+=av.w*w1; acc[3][2]+=av.w*w2;
    }
    __syncthreads();
  }
  // scatter: o<16 -> sd (LDS), 16..31 -> Bm, 32..47 -> Cm
  #pragma unroll
  for (int i=0;i<4;i++){
    int trow = ty*4 + i;
    size_t tok = (size_t)(tile*64 + trow);
    #pragma unroll
    for (int j=0;j<3;j++){
      int o = tx*3 + j;
      float v = acc[i][j];
      if (o < 16)      sd[trow][o] = v;
      else if (o < 32) bm[tok*NS + (o-16)] = v;
      else             cm[tok*NS + (o-32)] = v;
    }
  }
  __syncthreads();
  // dtproj: d = tid, rank-16 over sd rows
  float4 dw0 = *(const float4*)(dtw + (size_t)tid*16 + 0);
  float4 dw1 = *(const float4*)(dtw + (size_t)tid*16 + 4);
  float4 dw2 = *(const float4*)(dtw + (size_t)tid*16 + 8);
  float4 dw3 = *(const float4*)(dtw + (size_t)tid*16 + 12);
  float bias = dbi[tid];
  for (int trow=0;trow<64;trow++){
    float4 s0 = *(const float4*)&sd[trow][0];
    float4 s1 = *(const float4*)&sd[trow][4];
    float4 s2 = *(const float4*)&sd[trow][8];
    float4 s3 = *(const float4*)&sd[trow][12];
    float a = bias;
    a += s0.x*dw0.x + s0.y*dw0.y + s0.z*dw0.z + s0.w*dw0.w;
    a += s1.x*dw1.x + s1.y*dw1.y + s1.z*dw1.z + s1.w*dw1.w;
    a += s2.x*dw2.x + s2.y*dw2.y + s2.z*dw2.z + s2.w*dw2.w;
    a += s3.x*dw3.x + s3.y*dw3.y + s3.z*dw3.z + s3.w*dw3.w;
    dt[(size_t)(tile*64 + trow)*DM + tid] = softplus_(a);
  }
}

// ---------- scan phase 1: per-chunk summaries (Aprod, h_end) ----------
__global__ __launch_bounds__(256) void k_scan1(
    const float* __restrict__ dtf, const float* __restrict__ dtb,
    const float* __restrict__ uf, const float* __restrict__ ub,
    const float* __restrict__ bmf, const float* __restrict__ bmb,
    const float* __restrict__ alog_f, const float* __restrict__ alog_b,
    float* __restrict__ apf, float* __restrict__ hsf,
    float* __restrict__ apb, float* __restrict__ hsb)
{
  int c = blockIdx.x, b = blockIdx.y, dir = blockIdx.z;
  const float* dt = dir? dtb : dtf;
  const float* u  = dir? ub  : uf;
  const float* bmp= dir? bmb : bmf;
  const float* al = dir? alog_b : alog_f;
  float* ap = dir? apb : apf;
  float* hs = dir? hsb : hsf;
  int d = threadIdx.x;
  __shared__ float sB[CHL*NS];
  for (int i=threadIdx.x;i<CHL*NS;i+=256) sB[i] = bmp[((size_t)b*SQ + c*CHL)*NS + i];
  float A[NS];
  #pragma unroll
  for (int n=0;n<NS;n++) A[n] = -__expf(al[d*NS+n]);
  float h[NS] = {};
  float dts = 0.f;
  __syncthreads();
  for (int t=0;t<CHL;t++){
    size_t idx = ((size_t)b*SQ + c*CHL + t)*DM + d;
    float dtv = dt[idx];
    float uv  = u[idx];
    float du  = dtv*uv;
    dts += dtv;
    #pragma unroll
    for (int n=0;n<NS;n++) h[n] = h[n]*__expf(dtv*A[n]) + du*sB[t*NS+n];
  }
  size_t o = (((size_t)b*NCHK + c)*DM + d)*NS;
  #pragma unroll
  for (int n=0;n<NS;n++){ hs[o+n] = h[n]; ap[o+n] = __expf(A[n]*dts); }
}

// ---------- scan phase 2: sequential scan over chunk summaries (in place -> prefixes) ----------
__global__ __launch_bounds__(256) void k_scan2(
    float* __restrict__ apf, float* __restrict__ hsf,
    float* __restrict__ apb, float* __restrict__ hsb)
{
  int gid = blockIdx.x*256 + threadIdx.x;     // 0..16383
  int dir = gid >> 13;
  int rem = gid & 8191;
  int b   = rem >> 12;
  int dn  = rem & 4095;
  const float* ap = dir? apb : apf;
  float* hs = dir? hsb : hsf;
  float h = 0.f;
  for (int c=0;c<NCHK;c++){
    size_t idx = ((size_t)b*NCHK + c)*4096 + dn;
    float a = ap[idx];
    float v = hs[idx];
    hs[idx] = h;          // prefix (state entering chunk c)
    h = h*a + v;
  }
}

// ---------- scan phase 3: replay with prefix, emit y ----------
__global__ __launch_bounds__(256) void k_scan3(
    const float* __restrict__ dt, const float* __restrict__ u,
    const float* __restrict__ bmp, const float* __restrict__ cmp,
    const float* __restrict__ al, const float* __restrict__ Dv,
    const float* __restrict__ z, const float* __restrict__ hs,
    float* __restrict__ yout, int dir)
{
  int c = blockIdx.x, b = blockIdx.y;
  int d = threadIdx.x;
  __shared__ float sB[CHL*NS];
  __shared__ float sC[CHL*NS];
  for (int i=threadIdx.x;i<CHL*NS;i+=256){
    sB[i] = bmp[((size_t)b*SQ + c*CHL)*NS + i];
    sC[i] = cmp[((size_t)b*SQ + c*CHL)*NS + i];
  }
  float A[NS], h[NS];
  size_t o = (((size_t)b*NCHK + c)*DM + d)*NS;
  #pragma unroll
  for (int n=0;n<NS;n++){ A[n] = -__expf(al[d*NS+n]); h[n] = hs[o+n]; }
  float Dd = Dv[d];
  __syncthreads();
  for (int t=0;t<CHL;t++){
    int gt = c*CHL + t;
    size_t idx = ((size_t)b*SQ + gt)*DM + d;
    float dtv = dt[idx];
    float uv  = u[idx];
    float du  = dtv*uv;
    float y = 0.f;
    #pragma unroll
    for (int n=0;n<NS;n++){
      h[n] = h[n]*__expf(dtv*A[n]) + du*sB[t*NS+n];
      y += h[n]*sC[t*NS+n];
    }
    y += uv*Dd;
    int torig = dir ? (SQ-1-gt) : gt;
    size_t oidx = ((size_t)b*SQ + torig)*DM + d;
    float zv = z[oidx];
    yout[oidx] = y * (zv * sigm_(zv));
  }
}

// ---------- final: LN(y) @ out_proj.T -> LN -> + skip ----------
__global__ __launch_bounds__(256) void k_final(
    const float* __restrict__ yf, const float* __restrict__ yb,
    const float* __restrict__ meanY, const float* __restrict__ rstdY,
    const float* __restrict__ og, const float* __restrict__ ob,
    const float* __restrict__ Wout,
    const float* __restrict__ pg, const float* __restrict__ pb,
    const float* __restrict__ skip, float* __restrict__ out)
{
  __shared__ float Yn[16*16];
  __shared__ float Ws[256*17];
  __shared__ float sOut[16*256];
  __shared__ float sm[16], sr[16];
  int tt = blockIdx.x;
  int tid = threadIdx.x;
  float acc[16] = {};
  int i = tid>>4, kk = tid&15;
  int tok_i = tt*16 + i;
  float mI = meanY[tok_i], rI = rstdY[tok_i];
  for (int k0=0;k0<DM;k0+=16){
    float v = 0.5f*(yf[(size_t)tok_i*DM+k0+kk] + yb[(size_t)tok_i*DM+k0+kk]);
    Yn[i*16+kk] = (v - mI)*rI*og[k0+kk] + ob[k0+kk];
    const float* wr = Wout + (size_t)tid*DM + k0;
    #pragma unroll
    for (int e=0;e<16;e++) Ws[tid*17+e] = wr[e];
    __syncthreads();
    #pragma unroll
    for (int k2=0;k2<16;k2++){
      float w = Ws[tid*17+k2];
      #pragma unroll
      for (int t=0;t<16;t++) acc[t] += Yn[t*16+k2]*w;
    }
    __syncthreads();
  }
  #pragma unroll
  for (int t=0;t<16;t++) sOut[t*256+tid] = acc[t];
  __syncthreads();
  int wv = tid>>6, lane = tid&63;
  for (int j=0;j<4;j++){
    int t = wv*4+j;
    float s=0.f, ss=0.f;
    #pragma unroll
    for (int q=0;q<4;q++){ float v=sOut[t*256+lane+64*q]; s+=v; ss+=v*v; }
    #pragma unroll
    for (int o=32;o>0;o>>=1){ s += __shfl_xor(s,o,64); ss += __shfl_xor(ss,o,64); }
    if (lane==0){ float m=s*(1.f/DM); sm[t]=m; sr[t]=rsqrtf(ss*(1.f/DM)-m*m+1e-5f); }
  }
  __syncthreads();
  float gv = pg[tid], bv = pb[tid];
  for (int t=0;t<16;t++){
    int tok = tt*16+t;
    float v = (sOut[t*256+tid]-sm[t])*sr[t]*gv + bv + skip[(size_t)tok*DM+tid];
    out[(size_t)tok*DM+tid] = v;
  }
}

extern "C" void kernel_launch(void* const* d_in, const int* in_sizes, int n_in,
                              void* d_out, int out_size, void* d_ws, size_t ws_size,
                              hipStream_t stream)
{
  const float* input      = (const float*)d_in[0];
  const float* norm_g     = (const float*)d_in[1];
  const float* norm_b     = (const float*)d_in[2];
  const float* in_proj_w  = (const float*)d_in[3];
  const float* conv_w     = (const float*)d_in[4];
  const float* conv_b     = (const float*)d_in[5];
  const float* xproj_w    = (const float*)d_in[6];
  const float* dtproj_w   = (const float*)d_in[7];
  const float* dtproj_b   = (const float*)d_in[8];
  const float* A_log      = (const float*)d_in[9];
  const float* Dp         = (const float*)d_in[10];
  const float* conv_w_b   = (const float*)d_in[11];
  const float* conv_b_b   = (const float*)d_in[12];
  const float* xproj_w_b  = (const float*)d_in[13];
  const float* dtproj_w_b = (const float*)d_in[14];
  const float* dtproj_b_b = (const float*)d_in[15];
  const float* A_log_b    = (const float*)d_in[16];
  const float* Dp_b       = (const float*)d_in[17];
  const float* out_norm_g = (const float*)d_in[18];
  const float* out_norm_b = (const float*)d_in[19];
  const float* out_proj_w = (const float*)d_in[20];
  const float* post_norm_g= (const float*)d_in[21];
  const float* post_norm_b= (const float*)d_in[22];
  float* out = (float*)d_out;

  float* ws = (float*)d_ws;
  const size_t M2 = (size_t)NTOK*DM;       // 2M floats
  float* xin = ws;                // later reused as y_f
  float* z   = ws + M2;
  float* uf  = ws + 2*M2;         // later reused as y_b
  float* ub  = ws + 3*M2;
  float* dtf = ws + 4*M2;
  float* dtb = ws + 5*M2;
  float* p   = ws + 6*M2;
  float* bmf = p;              p += (size_t)NTOK*NS;
  float* cmf = p;              p += (size_t)NTOK*NS;
  float* bmb = p;              p += (size_t)NTOK*NS;
  float* cmb = p;              p += (size_t)NTOK*NS;
  float* apf = p;              p += (size_t)BT*NCHK*DM*NS;
  float* hsf = p;              p += (size_t)BT*NCHK*DM*NS;
  float* apb = p;              p += (size_t)BT*NCHK*DM*NS;
  float* hsb = p;              p += (size_t)BT*NCHK*DM*NS;
  float* meanX = p;            p += NTOK;
  float* rstdX = p;            p += NTOK;
  float* meanY = p;            p += NTOK;
  float* rstdY = p;            p += NTOK;
  float* yf = xin;
  float* yb = uf;

  k_stats_in<<<NTOK/4, 256, 0, stream>>>(input, meanX, rstdX);
  k_inproj<<<dim3(NTOK/64, 8, 1), 256, 0, stream>>>(input, meanX, rstdX, norm_g, norm_b,
                                                    in_proj_w, xin, z);
  k_conv<<<dim3(SQ/16, BT, 2), 256, 0, stream>>>(xin, conv_w, conv_b, conv_w_b, conv_b_b, uf, ub);
  k_xproj<<<dim3(NTOK/64, 2, 1), 256, 0, stream>>>(uf, ub, xproj_w, xproj_w_b,
                                                   dtproj_w, dtproj_w_b, dtproj_b, dtproj_b_b,
                                                   dtf, dtb, bmf, cmf, bmb, cmb);
  k_scan1<<<dim3(NCHK, BT, 2), 256, 0, stream>>>(dtf, dtb, uf, ub, bmf, bmb, A_log, A_log_b,
                                                 apf, hsf, apb, hsb);
  k_scan2<<<64, 256, 0, stream>>>(apf, hsf, apb, hsb);
  // fwd writes y_f into xin (xin dead); bwd writes y_b into uf (uf dead after fwd) -> ordered launches
  k_scan3<<<dim3(NCHK, BT, 1), 256, 0, stream>>>(dtf, uf, bmf, cmf, A_log, Dp, z, hsf, yf, 0);
  k_scan3<<<dim3(NCHK, BT, 1), 256, 0, stream>>>(dtb, ub, bmb, cmb, A_log_b, Dp_b, z, hsb, yb, 1);
  k_stats_y<<<NTOK/4, 256, 0, stream>>>(yf, yb, meanY, rstdY);
  k_final<<<NTOK/16, 256, 0, stream>>>(yf, yb, meanY, rstdY, out_norm_g, out_norm_b,
                                       out_proj_w, post_norm_g, post_norm_b, input, out);
}

// Round 3
// 221.132 us; speedup vs baseline: 1.6987x; 1.4077x over previous
//
#include <hip/hip_runtime.h>
#include <math.h>

#define DM 256
#define SQ 4096
#define BT 2
#define NS 16
#define NTOK (BT*SQ)
#define NCHK 64
#define CHL (SQ/NCHK)

typedef __attribute__((ext_vector_type(8))) short short8;
typedef __attribute__((ext_vector_type(4))) float f32x4;

__device__ __forceinline__ float sigm_(float x){ return 1.f/(1.f+__expf(-x)); }
__device__ __forceinline__ float silu_(float x){ return x*sigm_(x); }
__device__ __forceinline__ float softplus_(float x){ return (x>20.f)? x : log1pf(__expf(x)); }
__device__ __forceinline__ unsigned short f2bf(float f){
  unsigned int u = __float_as_uint(f);
  unsigned int r = (u + 0x7FFFu + ((u>>16)&1u)) >> 16;
  return (unsigned short)r;
}

// ---------- fused LN stats + apply + bf16 convert: one wave per token ----------
__global__ __launch_bounds__(256) void k_lncvt(const float* __restrict__ x,
                                               const float* __restrict__ g, const float* __restrict__ nb,
                                               unsigned short* __restrict__ xl){
  int tok = blockIdx.x*4 + (threadIdx.x>>6);
  int lane = threadIdx.x & 63;
  const float* row = x + (size_t)tok*DM;
  float4 v = *(const float4*)(row + lane*4);
  float s = v.x+v.y+v.z+v.w;
  float ss = v.x*v.x+v.y*v.y+v.z*v.z+v.w*v.w;
  #pragma unroll
  for (int o=32;o>0;o>>=1){ s += __shfl_xor(s,o,64); ss += __shfl_xor(ss,o,64); }
  float m = s*(1.f/DM);
  float r = rsqrtf(ss*(1.f/DM)-m*m+1e-5f);
  float4 gv = *(const float4*)(g + lane*4);
  float4 bv = *(const float4*)(nb + lane*4);
  ushort4 o4;
  o4.x = f2bf((v.x-m)*r*gv.x+bv.x);
  o4.y = f2bf((v.y-m)*r*gv.y+bv.y);
  o4.z = f2bf((v.z-m)*r*gv.z+bv.z);
  o4.w = f2bf((v.w-m)*r*gv.w+bv.w);
  *(ushort4*)(xl + (size_t)tok*DM + lane*4) = o4;
}

// ---------- W (512x256) fp32 -> bf16 ----------
__global__ __launch_bounds__(256) void k_wcvt(const float* __restrict__ W, unsigned short* __restrict__ Wb){
  int i = (blockIdx.x*256 + threadIdx.x)*4;
  float4 v = *(const float4*)(W + i);
  ushort4 o4; o4.x=f2bf(v.x); o4.y=f2bf(v.y); o4.z=f2bf(v.z); o4.w=f2bf(v.w);
  *(ushort4*)(Wb + i) = o4;
}

// ---------- in_proj via MFMA: C[8192][512] = xl @ Wb^T, split into xin|z ----------
// block: 128 tokens x 64 outs, 4 waves (2x2), no LDS, K fully in-register from global (L1/L2 hot)
__global__ __launch_bounds__(256) void k_inproj_mfma(
    const unsigned short* __restrict__ xl, const unsigned short* __restrict__ Wb,
    float* __restrict__ xin, float* __restrict__ z)
{
  int tid = threadIdx.x;
  int wid = tid >> 6, lane = tid & 63;
  int wm = wid >> 1, wn = wid & 1;
  int row0 = blockIdx.x*128 + wm*64;
  int col0 = blockIdx.y*64 + wn*32;      // global output col 0..511
  int lr = lane & 15;
  int lg = lane >> 4;
  f32x4 acc[4][2];
  #pragma unroll
  for (int m=0;m<4;m++)
    #pragma unroll
    for (int n=0;n<2;n++) acc[m][n] = (f32x4){0.f,0.f,0.f,0.f};

  #pragma unroll
  for (int k0=0;k0<DM;k0+=32){
    short8 a[4], b[2];
    #pragma unroll
    for (int m=0;m<4;m++)
      a[m] = *(const short8*)(xl + (size_t)(row0 + m*16 + lr)*DM + k0 + lg*8);
    #pragma unroll
    for (int n=0;n<2;n++)
      b[n] = *(const short8*)(Wb + (size_t)(col0 + n*16 + lr)*DM + k0 + lg*8);
    #pragma unroll
    for (int m=0;m<4;m++)
      #pragma unroll
      for (int n=0;n<2;n++)
        acc[m][n] = __builtin_amdgcn_mfma_f32_16x16x32_bf16(a[m], b[n], acc[m][n], 0,0,0);
  }
  float* outp; int cb;
  if (blockIdx.y < 4){ outp = xin; cb = col0; } else { outp = z; cb = col0 - 256; }
  #pragma unroll
  for (int m=0;m<4;m++)
    #pragma unroll
    for (int n=0;n<2;n++)
      #pragma unroll
      for (int r=0;r<4;r++){
        int rr = row0 + m*16 + lg*4 + r;
        int cc = cb + n*16 + lr;
        outp[(size_t)rr*DM + cc] = acc[m][n][r];
      }
}

// ---------- causal depthwise conv (K=4) + silu, rolling window ----------
__global__ __launch_bounds__(256) void k_conv(
    const float* __restrict__ xin,
    const float* __restrict__ cw_f, const float* __restrict__ cb_f,
    const float* __restrict__ cw_b, const float* __restrict__ cb_b,
    float* __restrict__ uf, float* __restrict__ ub)
{
  int d = threadIdx.x;
  int b = blockIdx.y;
  int dir = blockIdx.z;
  int t0 = blockIdx.x*16;
  const float* w  = dir? cw_b : cw_f;
  const float* bi = dir? cb_b : cb_f;
  float w0=w[d*4], w1=w[d*4+1], w2=w[d*4+2], w3=w[d*4+3];
  float bb = bi[d];
  float* out = dir? ub : uf;
  const float* xbase = xin + (size_t)b*SQ*DM + d;
  float xm3 = (t0-3>=0)? xbase[(size_t)(dir?(SQ-1-(t0-3)):(t0-3))*DM] : 0.f;
  float xm2 = (t0-2>=0)? xbase[(size_t)(dir?(SQ-1-(t0-2)):(t0-2))*DM] : 0.f;
  float xm1 = (t0-1>=0)? xbase[(size_t)(dir?(SQ-1-(t0-1)):(t0-1))*DM] : 0.f;
  for (int i=0;i<16;i++){
    int t = t0+i;
    float xt = xbase[(size_t)(dir?(SQ-1-t):t)*DM];
    out[((size_t)b*SQ+t)*DM + d] = silu_(bb + w0*xm3 + w1*xm2 + w2*xm1 + w3*xt);
    xm3=xm2; xm2=xm1; xm1=xt;
  }
}

// ---------- xproj GEMM (M=64 tokens/block, N=48, K=256) + fused dtproj + softplus ----------
__global__ __launch_bounds__(256) void k_xproj(
    const float* __restrict__ uf, const float* __restrict__ ub,
    const float* __restrict__ xw_f, const float* __restrict__ xw_b,
    const float* __restrict__ dtw_f, const float* __restrict__ dtw_b,
    const float* __restrict__ dtbias_f, const float* __restrict__ dtbias_b,
    float* __restrict__ dtf, float* __restrict__ dtb,
    float* __restrict__ bmf, float* __restrict__ cmf,
    float* __restrict__ bmb, float* __restrict__ cmb)
{
  int tile = blockIdx.x;
  int dir  = blockIdx.y;
  const float* u   = dir? ub : uf;
  const float* xw  = dir? xw_b : xw_f;
  const float* dtw = dir? dtw_b : dtw_f;
  const float* dbi = dir? dtbias_b : dtbias_f;
  float* dt = dir? dtb : dtf;
  float* bm = dir? bmb : bmf;
  float* cm = dir? cmb : cmf;

  __shared__ float As[32][68];
  __shared__ float Ws[48][33];
  __shared__ float sd[64][20];

  int tid = threadIdx.x;
  int tx = tid & 15;
  int ty = tid >> 4;
  int li = tid >> 2;
  int lk = (tid & 3) * 8;

  float acc[4][3] = {};
  for (int k0 = 0; k0 < DM; k0 += 32){
    const float* up = u + (size_t)(tile*64 + li)*DM + k0 + lk;
    float4 a0 = *(const float4*)(up);
    float4 a1 = *(const float4*)(up+4);
    As[lk+0][li]=a0.x; As[lk+1][li]=a0.y; As[lk+2][li]=a0.z; As[lk+3][li]=a0.w;
    As[lk+4][li]=a1.x; As[lk+5][li]=a1.y; As[lk+6][li]=a1.z; As[lk+7][li]=a1.w;
    if (tid < 192){
      int wr = tid >> 2;
      int wk = (tid & 3) * 8;
      const float* wp = xw + (size_t)wr*DM + k0 + wk;
      float4 w0 = *(const float4*)(wp);
      float4 w1 = *(const float4*)(wp+4);
      Ws[wr][wk+0]=w0.x; Ws[wr][wk+1]=w0.y; Ws[wr][wk+2]=w0.z; Ws[wr][wk+3]=w0.w;
      Ws[wr][wk+4]=w1.x; Ws[wr][wk+5]=w1.y; Ws[wr][wk+6]=w1.z; Ws[wr][wk+7]=w1.w;
    }
    __syncthreads();
    #pragma unroll
    for (int k=0;k<32;k++){
      float4 av = *(const float4*)&As[k][ty*4];
      float w0 = Ws[tx*3+0][k], w1 = Ws[tx*3+1][k], w2 = Ws[tx*3+2][k];
      acc[0][0]+=av.x*w0; acc[0][1]+=av.x*w1; acc[0][2]+=av.x*w2;
      acc[1][0]+=av.y*w0; acc[1][1]+=av.y*w1; acc[1][2]+=av.y*w2;
      acc[2][0]+=av.z*w0; acc[2][1]+=av.z*w1; acc[2][2]+=av.z*w2;
      acc[3][0]+=av.w*w0; acc[3][1]+=av.w*w1; acc[3][2]+=av.w*w2;
    }
    __syncthreads();
  }
  #pragma unroll
  for (int i=0;i<4;i++){
    int trow = ty*4 + i;
    size_t tok = (size_t)(tile*64 + trow);
    #pragma unroll
    for (int j=0;j<3;j++){
      int o = tx*3 + j;
      float v = acc[i][j];
      if (o < 16)      sd[trow][o] = v;
      else if (o < 32) bm[tok*NS + (o-16)] = v;
      else             cm[tok*NS + (o-32)] = v;
    }
  }
  __syncthreads();
  float4 dw0 = *(const float4*)(dtw + (size_t)tid*16 + 0);
  float4 dw1 = *(const float4*)(dtw + (size_t)tid*16 + 4);
  float4 dw2 = *(const float4*)(dtw + (size_t)tid*16 + 8);
  float4 dw3 = *(const float4*)(dtw + (size_t)tid*16 + 12);
  float bias = dbi[tid];
  for (int trow=0;trow<64;trow++){
    float4 s0 = *(const float4*)&sd[trow][0];
    float4 s1 = *(const float4*)&sd[trow][4];
    float4 s2 = *(const float4*)&sd[trow][8];
    float4 s3 = *(const float4*)&sd[trow][12];
    float a = bias;
    a += s0.x*dw0.x + s0.y*dw0.y + s0.z*dw0.z + s0.w*dw0.w;
    a += s1.x*dw1.x + s1.y*dw1.y + s1.z*dw1.z + s1.w*dw1.w;
    a += s2.x*dw2.x + s2.y*dw2.y + s2.z*dw2.z + s2.w*dw2.w;
    a += s3.x*dw3.x + s3.y*dw3.y + s3.z*dw3.z + s3.w*dw3.w;
    dt[(size_t)(tile*64 + trow)*DM + tid] = softplus_(a);
  }
}

// ---------- scan phase 1: per-chunk summaries (Aprod, h_end) ----------
__global__ __launch_bounds__(256) void k_scan1(
    const float* __restrict__ dtf, const float* __restrict__ dtb,
    const float* __restrict__ uf, const float* __restrict__ ub,
    const float* __restrict__ bmf, const float* __restrict__ bmb,
    const float* __restrict__ alog_f, const float* __restrict__ alog_b,
    float* __restrict__ apf, float* __restrict__ hsf,
    float* __restrict__ apb, float* __restrict__ hsb)
{
  int c = blockIdx.x, b = blockIdx.y, dir = blockIdx.z;
  const float* dt = dir? dtb : dtf;
  const float* u  = dir? ub  : uf;
  const float* bmp= dir? bmb : bmf;
  const float* al = dir? alog_b : alog_f;
  float* ap = dir? apb : apf;
  float* hs = dir? hsb : hsf;
  int d = threadIdx.x;
  __shared__ float sB[CHL*NS];
  for (int i=threadIdx.x;i<CHL*NS;i+=256) sB[i] = bmp[((size_t)b*SQ + c*CHL)*NS + i];
  float A[NS];
  #pragma unroll
  for (int n=0;n<NS;n++) A[n] = -__expf(al[d*NS+n]);
  float h[NS] = {};
  float dts = 0.f;
  __syncthreads();
  for (int t=0;t<CHL;t++){
    size_t idx = ((size_t)b*SQ + c*CHL + t)*DM + d;
    float dtv = dt[idx];
    float uv  = u[idx];
    float du  = dtv*uv;
    dts += dtv;
    #pragma unroll
    for (int n=0;n<NS;n++) h[n] = h[n]*__expf(dtv*A[n]) + du*sB[t*NS+n];
  }
  size_t o = (((size_t)b*NCHK + c)*DM + d)*NS;
  #pragma unroll
  for (int n=0;n<NS;n++){ hs[o+n] = h[n]; ap[o+n] = __expf(A[n]*dts); }
}

// ---------- scan phase 2: sequential scan over chunk summaries ----------
__global__ __launch_bounds__(256) void k_scan2(
    float* __restrict__ apf, float* __restrict__ hsf,
    float* __restrict__ apb, float* __restrict__ hsb)
{
  int gid = blockIdx.x*256 + threadIdx.x;
  int dir = gid >> 13;
  int rem = gid & 8191;
  int b   = rem >> 12;
  int dn  = rem & 4095;
  const float* ap = dir? apb : apf;
  float* hs = dir? hsb : hsf;
  float h = 0.f;
  for (int c=0;c<NCHK;c++){
    size_t idx = ((size_t)b*NCHK + c)*4096 + dn;
    float a = ap[idx];
    float v = hs[idx];
    hs[idx] = h;
    h = h*a + v;
  }
}

// ---------- scan phase 3: replay with prefix, emit y (both dirs) ----------
__global__ __launch_bounds__(256) void k_scan3(
    const float* __restrict__ dtf, const float* __restrict__ dtb,
    const float* __restrict__ uf, const float* __restrict__ ub,
    const float* __restrict__ bmf, const float* __restrict__ bmb,
    const float* __restrict__ cmf, const float* __restrict__ cmb,
    const float* __restrict__ alf, const float* __restrict__ alb,
    const float* __restrict__ Df, const float* __restrict__ Db,
    const float* __restrict__ z,
    const float* __restrict__ hsf, const float* __restrict__ hsb,
    float* __restrict__ yf, float* __restrict__ yb, int dir_base)
{
  int c = blockIdx.x, b = blockIdx.y;
  int dir = blockIdx.z + dir_base;
  const float* dt = dir? dtb : dtf;
  const float* u  = dir? ub  : uf;
  const float* bmp= dir? bmb : bmf;
  const float* cmp= dir? cmb : cmf;
  const float* al = dir? alb : alf;
  const float* Dv = dir? Db  : Df;
  const float* hs = dir? hsb : hsf;
  float* yout = dir? yb : yf;
  int d = threadIdx.x;
  __shared__ float sB[CHL*NS];
  __shared__ float sC[CHL*NS];
  for (int i=threadIdx.x;i<CHL*NS;i+=256){
    sB[i] = bmp[((size_t)b*SQ + c*CHL)*NS + i];
    sC[i] = cmp[((size_t)b*SQ + c*CHL)*NS + i];
  }
  float A[NS], h[NS];
  size_t o = (((size_t)b*NCHK + c)*DM + d)*NS;
  #pragma unroll
  for (int n=0;n<NS;n++){ A[n] = -__expf(al[d*NS+n]); h[n] = hs[o+n]; }
  float Dd = Dv[d];
  __syncthreads();
  for (int t=0;t<CHL;t++){
    int gt = c*CHL + t;
    size_t idx = ((size_t)b*SQ + gt)*DM + d;
    float dtv = dt[idx];
    float uv  = u[idx];
    float du  = dtv*uv;
    float y = 0.f;
    #pragma unroll
    for (int n=0;n<NS;n++){
      h[n] = h[n]*__expf(dtv*A[n]) + du*sB[t*NS+n];
      y += h[n]*sC[t*NS+n];
    }
    y += uv*Dd;
    int torig = dir ? (SQ-1-gt) : gt;
    size_t oidx = ((size_t)b*SQ + torig)*DM + d;
    float zv = z[oidx];
    yout[oidx] = y * (zv * sigm_(zv));
  }
}

// ---------- y-combine LN stats ----------
__global__ __launch_bounds__(256) void k_stats_y(const float* __restrict__ yf, const float* __restrict__ yb,
                                                 float* __restrict__ mean, float* __restrict__ rstd){
  int tok = blockIdx.x*4 + (threadIdx.x>>6);
  int lane = threadIdx.x & 63;
  size_t base = (size_t)tok*DM;
  float s=0.f, ss=0.f;
  #pragma unroll
  for (int j=0;j<4;j++){ int c=lane+64*j; float v=0.5f*(yf[base+c]+yb[base+c]); s+=v; ss+=v*v; }
  #pragma unroll
  for (int o=32;o>0;o>>=1){ s += __shfl_xor(s,o,64); ss += __shfl_xor(ss,o,64); }
  if (lane==0){ float m=s*(1.f/DM); float v=ss*(1.f/DM)-m*m; mean[tok]=m; rstd[tok]=rsqrtf(v+1e-5f); }
}

// ---------- final: LN(y) @ out_proj.T -> LN -> + skip ----------
__global__ __launch_bounds__(256) void k_final(
    const float* __restrict__ yf, const float* __restrict__ yb,
    const float* __restrict__ meanY, const float* __restrict__ rstdY,
    const float* __restrict__ og, const float* __restrict__ ob,
    const float* __restrict__ Wout,
    const float* __restrict__ pg, const float* __restrict__ pb,
    const float* __restrict__ skip, float* __restrict__ out)
{
  __shared__ float Yn[16*16];
  __shared__ float Ws[256*17];
  __shared__ float sOut[16*256];
  __shared__ float sm[16], sr[16];
  int tt = blockIdx.x;
  int tid = threadIdx.x;
  float acc[16] = {};
  int i = tid>>4, kk = tid&15;
  int tok_i = tt*16 + i;
  float mI = meanY[tok_i], rI = rstdY[tok_i];
  for (int k0=0;k0<DM;k0+=16){
    float v = 0.5f*(yf[(size_t)tok_i*DM+k0+kk] + yb[(size_t)tok_i*DM+k0+kk]);
    Yn[i*16+kk] = (v - mI)*rI*og[k0+kk] + ob[k0+kk];
    const float* wr = Wout + (size_t)tid*DM + k0;
    #pragma unroll
    for (int e=0;e<16;e++) Ws[tid*17+e] = wr[e];
    __syncthreads();
    #pragma unroll
    for (int k2=0;k2<16;k2++){
      float w = Ws[tid*17+k2];
      #pragma unroll
      for (int t=0;t<16;t++) acc[t] += Yn[t*16+k2]*w;
    }
    __syncthreads();
  }
  #pragma unroll
  for (int t=0;t<16;t++) sOut[t*256+tid] = acc[t];
  __syncthreads();
  int wv = tid>>6, lane = tid&63;
  for (int j=0;j<4;j++){
    int t = wv*4+j;
    float s=0.f, ss=0.f;
    #pragma unroll
    for (int q=0;q<4;q++){ float v=sOut[t*256+lane+64*q]; s+=v; ss+=v*v; }
    #pragma unroll
    for (int o=32;o>0;o>>=1){ s += __shfl_xor(s,o,64); ss += __shfl_xor(ss,o,64); }
    if (lane==0){ float m=s*(1.f/DM); sm[t]=m; sr[t]=rsqrtf(ss*(1.f/DM)-m*m+1e-5f); }
  }
  __syncthreads();
  float gv = pg[tid], bv = pb[tid];
  for (int t=0;t<16;t++){
    int tok = tt*16+t;
    float v = (sOut[t*256+tid]-sm[t])*sr[t]*gv + bv + skip[(size_t)tok*DM+tid];
    out[(size_t)tok*DM+tid] = v;
  }
}

extern "C" void kernel_launch(void* const* d_in, const int* in_sizes, int n_in,
                              void* d_out, int out_size, void* d_ws, size_t ws_size,
                              hipStream_t stream)
{
  const float* input      = (const float*)d_in[0];
  const float* norm_g     = (const float*)d_in[1];
  const float* norm_b     = (const float*)d_in[2];
  const float* in_proj_w  = (const float*)d_in[3];
  const float* conv_w     = (const float*)d_in[4];
  const float* conv_b     = (const float*)d_in[5];
  const float* xproj_w    = (const float*)d_in[6];
  const float* dtproj_w   = (const float*)d_in[7];
  const float* dtproj_b   = (const float*)d_in[8];
  const float* A_log      = (const float*)d_in[9];
  const float* Dp         = (const float*)d_in[10];
  const float* conv_w_b   = (const float*)d_in[11];
  const float* conv_b_b   = (const float*)d_in[12];
  const float* xproj_w_b  = (const float*)d_in[13];
  const float* dtproj_w_b = (const float*)d_in[14];
  const float* dtproj_b_b = (const float*)d_in[15];
  const float* A_log_b    = (const float*)d_in[16];
  const float* Dp_b       = (const float*)d_in[17];
  const float* out_norm_g = (const float*)d_in[18];
  const float* out_norm_b = (const float*)d_in[19];
  const float* out_proj_w = (const float*)d_in[20];
  const float* post_norm_g= (const float*)d_in[21];
  const float* post_norm_b= (const float*)d_in[22];
  float* out = (float*)d_out;

  float* ws = (float*)d_ws;
  const size_t M2 = (size_t)NTOK*DM;           // 2,097,152 floats
  const size_t SCH = (size_t)BT*NCHK*DM*NS;    // 524,288 floats
  float* xin = ws;                 // reused as y_f
  float* z   = ws + M2;
  float* uf  = ws + 2*M2;
  float* ub  = ws + 3*M2;
  float* dtf = ws + 4*M2;
  float* dtb = ws + 5*M2;
  float* p   = ws + 6*M2;
  float* bmf = p;              p += (size_t)NTOK*NS;
  float* cmf = p;              p += (size_t)NTOK*NS;
  float* bmb = p;              p += (size_t)NTOK*NS;
  float* cmb = p;              p += (size_t)NTOK*NS;
  float* apf = p;              p += SCH;
  float* hsf = p;              p += SCH;
  float* apb = p;              p += SCH;
  float* hsb = p;              p += SCH;
  float* meanY = p;            p += NTOK;
  float* rstdY = p;            p += NTOK;
  size_t base_floats = (size_t)(p - ws);
  // bf16 staging aliases (dead before scan1 writes ap/hs):
  unsigned short* xlbf = (unsigned short*)apf;   // 4 MB spans apf+hsf
  unsigned short* Wbf  = (unsigned short*)apb;   // 256 KB within apb
  // optional separate y_b buffer for fused scan3
  bool big = ws_size >= (base_floats + M2 + 1024)*sizeof(float);
  float* yf = xin;
  float* yb = big ? (ws + base_floats) : uf;

  k_lncvt<<<NTOK/4, 256, 0, stream>>>(input, norm_g, norm_b, xlbf);
  k_wcvt<<<(2*DM*DM)/1024, 256, 0, stream>>>(in_proj_w, Wbf);
  k_inproj_mfma<<<dim3(NTOK/128, 8, 1), 256, 0, stream>>>(xlbf, Wbf, xin, z);
  k_conv<<<dim3(SQ/16, BT, 2), 256, 0, stream>>>(xin, conv_w, conv_b, conv_w_b, conv_b_b, uf, ub);
  k_xproj<<<dim3(NTOK/64, 2, 1), 256, 0, stream>>>(uf, ub, xproj_w, xproj_w_b,
                                                   dtproj_w, dtproj_w_b, dtproj_b, dtproj_b_b,
                                                   dtf, dtb, bmf, cmf, bmb, cmb);
  k_scan1<<<dim3(NCHK, BT, 2), 256, 0, stream>>>(dtf, dtb, uf, ub, bmf, bmb, A_log, A_log_b,
                                                 apf, hsf, apb, hsb);
  k_scan2<<<64, 256, 0, stream>>>(apf, hsf, apb, hsb);
  if (big){
    k_scan3<<<dim3(NCHK, BT, 2), 256, 0, stream>>>(dtf, dtb, uf, ub, bmf, bmb, cmf, cmb,
                                                   A_log, A_log_b, Dp, Dp_b, z, hsf, hsb,
                                                   yf, yb, 0);
  } else {
    k_scan3<<<dim3(NCHK, BT, 1), 256, 0, stream>>>(dtf, dtb, uf, ub, bmf, bmb, cmf, cmb,
                                                   A_log, A_log_b, Dp, Dp_b, z, hsf, hsb,
                                                   yf, yb, 0);
    k_scan3<<<dim3(NCHK, BT, 1), 256, 0, stream>>>(dtf, dtb, uf, ub, bmf, bmb, cmf, cmb,
                                                   A_log, A_log_b, Dp, Dp_b, z, hsf, hsb,
                                                   yf, yb, 1);
  }
  k_stats_y<<<NTOK/4, 256, 0, stream>>>(yf, yb, meanY, rstdY);
  k_final<<<NTOK/16, 256, 0, stream>>>(yf, yb, meanY, rstdY, out_norm_g, out_norm_b,
                                       out_proj_w, post_norm_g, post_norm_b, input, out);
}

// Round 4
// 184.780 us; speedup vs baseline: 2.0329x; 1.1967x over previous
//
#include <hip/hip_runtime.h>
#include <math.h>

#define DM 256
#define SQ 4096
#define BT 2
#define NS 16
#define NTOK (BT*SQ)
#define NCHK 64
#define CHL (SQ/NCHK)

typedef __attribute__((ext_vector_type(8))) short short8;
typedef __attribute__((ext_vector_type(4))) float f32x4;

__device__ __forceinline__ float sigm_(float x){ return 1.f/(1.f+__expf(-x)); }
__device__ __forceinline__ float silu_(float x){ return x*sigm_(x); }
__device__ __forceinline__ float softplus_(float x){ return (x>20.f)? x : log1pf(__expf(x)); }
__device__ __forceinline__ unsigned short f2bf(float f){
  unsigned int u = __float_as_uint(f);
  unsigned int r = (u + 0x7FFFu + ((u>>16)&1u)) >> 16;
  return (unsigned short)r;
}

// ---------- fused LN stats + apply + bf16 convert: one wave per token ----------
__global__ __launch_bounds__(256) void k_lncvt(const float* __restrict__ x,
                                               const float* __restrict__ g, const float* __restrict__ nb,
                                               unsigned short* __restrict__ xl){
  int tok = blockIdx.x*4 + (threadIdx.x>>6);
  int lane = threadIdx.x & 63;
  const float* row = x + (size_t)tok*DM;
  float4 v = *(const float4*)(row + lane*4);
  float s = v.x+v.y+v.z+v.w;
  float ss = v.x*v.x+v.y*v.y+v.z*v.z+v.w*v.w;
  #pragma unroll
  for (int o=32;o>0;o>>=1){ s += __shfl_xor(s,o,64); ss += __shfl_xor(ss,o,64); }
  float m = s*(1.f/DM);
  float r = rsqrtf(ss*(1.f/DM)-m*m+1e-5f);
  float4 gv = *(const float4*)(g + lane*4);
  float4 bv = *(const float4*)(nb + lane*4);
  ushort4 o4;
  o4.x = f2bf((v.x-m)*r*gv.x+bv.x);
  o4.y = f2bf((v.y-m)*r*gv.y+bv.y);
  o4.z = f2bf((v.z-m)*r*gv.z+bv.z);
  o4.w = f2bf((v.w-m)*r*gv.w+bv.w);
  *(ushort4*)(xl + (size_t)tok*DM + lane*4) = o4;
}

// ---------- generic fp32 -> bf16 (size = grid*1024 elements) ----------
__global__ __launch_bounds__(256) void k_wcvt(const float* __restrict__ W, unsigned short* __restrict__ Wb){
  int i = (blockIdx.x*256 + threadIdx.x)*4;
  float4 v = *(const float4*)(W + i);
  ushort4 o4; o4.x=f2bf(v.x); o4.y=f2bf(v.y); o4.z=f2bf(v.z); o4.w=f2bf(v.w);
  *(ushort4*)(Wb + i) = o4;
}

// ---------- in_proj via MFMA: C[8192][512] = xl @ Wb^T, split into xin|z ----------
__global__ __launch_bounds__(256) void k_inproj_mfma(
    const unsigned short* __restrict__ xl, const unsigned short* __restrict__ Wb,
    float* __restrict__ xin, float* __restrict__ z)
{
  int tid = threadIdx.x;
  int wid = tid >> 6, lane = tid & 63;
  int wm = wid >> 1, wn = wid & 1;
  int row0 = blockIdx.x*128 + wm*64;
  int col0 = blockIdx.y*64 + wn*32;
  int lr = lane & 15;
  int lg = lane >> 4;
  f32x4 acc[4][2];
  #pragma unroll
  for (int m=0;m<4;m++)
    #pragma unroll
    for (int n=0;n<2;n++) acc[m][n] = (f32x4){0.f,0.f,0.f,0.f};

  #pragma unroll
  for (int k0=0;k0<DM;k0+=32){
    short8 a[4], b[2];
    #pragma unroll
    for (int m=0;m<4;m++)
      a[m] = *(const short8*)(xl + (size_t)(row0 + m*16 + lr)*DM + k0 + lg*8);
    #pragma unroll
    for (int n=0;n<2;n++)
      b[n] = *(const short8*)(Wb + (size_t)(col0 + n*16 + lr)*DM + k0 + lg*8);
    #pragma unroll
    for (int m=0;m<4;m++)
      #pragma unroll
      for (int n=0;n<2;n++)
        acc[m][n] = __builtin_amdgcn_mfma_f32_16x16x32_bf16(a[m], b[n], acc[m][n], 0,0,0);
  }
  float* outp; int cb;
  if (blockIdx.y < 4){ outp = xin; cb = col0; } else { outp = z; cb = col0 - 256; }
  #pragma unroll
  for (int m=0;m<4;m++)
    #pragma unroll
    for (int n=0;n<2;n++)
      #pragma unroll
      for (int r=0;r<4;r++){
        int rr = row0 + m*16 + lg*4 + r;
        int cc = cb + n*16 + lr;
        outp[(size_t)rr*DM + cc] = acc[m][n][r];
      }
}

// ---------- causal depthwise conv (K=4) + silu, rolling window ----------
__global__ __launch_bounds__(256) void k_conv(
    const float* __restrict__ xin,
    const float* __restrict__ cw_f, const float* __restrict__ cb_f,
    const float* __restrict__ cw_b, const float* __restrict__ cb_b,
    float* __restrict__ uf, float* __restrict__ ub)
{
  int d = threadIdx.x;
  int b = blockIdx.y;
  int dir = blockIdx.z;
  int t0 = blockIdx.x*16;
  const float* w  = dir? cw_b : cw_f;
  const float* bi = dir? cb_b : cb_f;
  float w0=w[d*4], w1=w[d*4+1], w2=w[d*4+2], w3=w[d*4+3];
  float bb = bi[d];
  float* out = dir? ub : uf;
  const float* xbase = xin + (size_t)b*SQ*DM + d;
  float xm3 = (t0-3>=0)? xbase[(size_t)(dir?(SQ-1-(t0-3)):(t0-3))*DM] : 0.f;
  float xm2 = (t0-2>=0)? xbase[(size_t)(dir?(SQ-1-(t0-2)):(t0-2))*DM] : 0.f;
  float xm1 = (t0-1>=0)? xbase[(size_t)(dir?(SQ-1-(t0-1)):(t0-1))*DM] : 0.f;
  for (int i=0;i<16;i++){
    int t = t0+i;
    float xt = xbase[(size_t)(dir?(SQ-1-t):t)*DM];
    out[((size_t)b*SQ+t)*DM + d] = silu_(bb + w0*xm3 + w1*xm2 + w2*xm1 + w3*xt);
    xm3=xm2; xm2=xm1; xm1=xt;
  }
}

// ---------- xproj GEMM (M=64 tokens/block, N=48, K=256) + fused dtproj + softplus ----------
__global__ __launch_bounds__(256) void k_xproj(
    const float* __restrict__ uf, const float* __restrict__ ub,
    const float* __restrict__ xw_f, const float* __restrict__ xw_b,
    const float* __restrict__ dtw_f, const float* __restrict__ dtw_b,
    const float* __restrict__ dtbias_f, const float* __restrict__ dtbias_b,
    float* __restrict__ dtf, float* __restrict__ dtb,
    float* __restrict__ bmf, float* __restrict__ cmf,
    float* __restrict__ bmb, float* __restrict__ cmb)
{
  int tile = blockIdx.x;
  int dir  = blockIdx.y;
  const float* u   = dir? ub : uf;
  const float* xw  = dir? xw_b : xw_f;
  const float* dtw = dir? dtw_b : dtw_f;
  const float* dbi = dir? dtbias_b : dtbias_f;
  float* dt = dir? dtb : dtf;
  float* bm = dir? bmb : bmf;
  float* cm = dir? cmb : cmf;

  __shared__ float As[32][68];
  __shared__ float Ws[48][33];
  __shared__ float sd[64][20];

  int tid = threadIdx.x;
  int tx = tid & 15;
  int ty = tid >> 4;
  int li = tid >> 2;
  int lk = (tid & 3) * 8;

  float acc[4][3] = {};
  for (int k0 = 0; k0 < DM; k0 += 32){
    const float* up = u + (size_t)(tile*64 + li)*DM + k0 + lk;
    float4 a0 = *(const float4*)(up);
    float4 a1 = *(const float4*)(up+4);
    As[lk+0][li]=a0.x; As[lk+1][li]=a0.y; As[lk+2][li]=a0.z; As[lk+3][li]=a0.w;
    As[lk+4][li]=a1.x; As[lk+5][li]=a1.y; As[lk+6][li]=a1.z; As[lk+7][li]=a1.w;
    if (tid < 192){
      int wr = tid >> 2;
      int wk = (tid & 3) * 8;
      const float* wp = xw + (size_t)wr*DM + k0 + wk;
      float4 w0 = *(const float4*)(wp);
      float4 w1 = *(const float4*)(wp+4);
      Ws[wr][wk+0]=w0.x; Ws[wr][wk+1]=w0.y; Ws[wr][wk+2]=w0.z; Ws[wr][wk+3]=w0.w;
      Ws[wr][wk+4]=w1.x; Ws[wr][wk+5]=w1.y; Ws[wr][wk+6]=w1.z; Ws[wr][wk+7]=w1.w;
    }
    __syncthreads();
    #pragma unroll
    for (int k=0;k<32;k++){
      float4 av = *(const float4*)&As[k][ty*4];
      float w0 = Ws[tx*3+0][k], w1 = Ws[tx*3+1][k], w2 = Ws[tx*3+2][k];
      acc[0][0]+=av.x*w0; acc[0][1]+=av.x*w1; acc[0][2]+=av.x*w2;
      acc[1][0]+=av.y*w0; acc[1][1]+=av.y*w1; acc[1][2]+=av.y*w2;
      acc[2][0]+=av.z*w0; acc[2][1]+=av.z*w1; acc[2][2]+=av.z*w2;
      acc[3][0]+=av.w*w0; acc[3][1]+=av.w*w1; acc[3][2]+=av.w*w2;
    }
    __syncthreads();
  }
  #pragma unroll
  for (int i=0;i<4;i++){
    int trow = ty*4 + i;
    size_t tok = (size_t)(tile*64 + trow);
    #pragma unroll
    for (int j=0;j<3;j++){
      int o = tx*3 + j;
      float v = acc[i][j];
      if (o < 16)      sd[trow][o] = v;
      else if (o < 32) bm[tok*NS + (o-16)] = v;
      else             cm[tok*NS + (o-32)] = v;
    }
  }
  __syncthreads();
  float4 dw0 = *(const float4*)(dtw + (size_t)tid*16 + 0);
  float4 dw1 = *(const float4*)(dtw + (size_t)tid*16 + 4);
  float4 dw2 = *(const float4*)(dtw + (size_t)tid*16 + 8);
  float4 dw3 = *(const float4*)(dtw + (size_t)tid*16 + 12);
  float bias = dbi[tid];
  for (int trow=0;trow<64;trow++){
    float4 s0 = *(const float4*)&sd[trow][0];
    float4 s1 = *(const float4*)&sd[trow][4];
    float4 s2 = *(const float4*)&sd[trow][8];
    float4 s3 = *(const float4*)&sd[trow][12];
    float a = bias;
    a += s0.x*dw0.x + s0.y*dw0.y + s0.z*dw0.z + s0.w*dw0.w;
    a += s1.x*dw1.x + s1.y*dw1.y + s1.z*dw1.z + s1.w*dw1.w;
    a += s2.x*dw2.x + s2.y*dw2.y + s2.z*dw2.z + s2.w*dw2.w;
    a += s3.x*dw3.x + s3.y*dw3.y + s3.z*dw3.z + s3.w*dw3.w;
    dt[(size_t)(tile*64 + trow)*DM + tid] = softplus_(a);
  }
}

// ---------- scan phase 1: per-chunk summaries (Aprod, h_end) ----------
__global__ __launch_bounds__(256) void k_scan1(
    const float* __restrict__ dtf, const float* __restrict__ dtb,
    const float* __restrict__ uf, const float* __restrict__ ub,
    const float* __restrict__ bmf, const float* __restrict__ bmb,
    const float* __restrict__ alog_f, const float* __restrict__ alog_b,
    float* __restrict__ apf, float* __restrict__ hsf,
    float* __restrict__ apb, float* __restrict__ hsb)
{
  int c = blockIdx.x, b = blockIdx.y, dir = blockIdx.z;
  const float* dt = dir? dtb : dtf;
  const float* u  = dir? ub  : uf;
  const float* bmp= dir? bmb : bmf;
  const float* al = dir? alog_b : alog_f;
  float* ap = dir? apb : apf;
  float* hs = dir? hsb : hsf;
  int d = threadIdx.x;
  __shared__ float sB[CHL*NS];
  for (int i=threadIdx.x;i<CHL*NS;i+=256) sB[i] = bmp[((size_t)b*SQ + c*CHL)*NS + i];
  float A[NS];
  #pragma unroll
  for (int n=0;n<NS;n++) A[n] = -__expf(al[d*NS+n]);
  float h[NS] = {};
  float dts = 0.f;
  __syncthreads();
  for (int t=0;t<CHL;t++){
    size_t idx = ((size_t)b*SQ + c*CHL + t)*DM + d;
    float dtv = dt[idx];
    float uv  = u[idx];
    float du  = dtv*uv;
    dts += dtv;
    #pragma unroll
    for (int n=0;n<NS;n++) h[n] = h[n]*__expf(dtv*A[n]) + du*sB[t*NS+n];
  }
  size_t o = (((size_t)b*NCHK + c)*DM + d)*NS;
  #pragma unroll
  for (int n=0;n<NS;n++){ hs[o+n] = h[n]; ap[o+n] = __expf(A[n]*dts); }
}

// ---------- scan phase 2: sequential scan over chunk summaries ----------
__global__ __launch_bounds__(256) void k_scan2(
    float* __restrict__ apf, float* __restrict__ hsf,
    float* __restrict__ apb, float* __restrict__ hsb)
{
  int gid = blockIdx.x*256 + threadIdx.x;
  int dir = gid >> 13;
  int rem = gid & 8191;
  int b   = rem >> 12;
  int dn  = rem & 4095;
  const float* ap = dir? apb : apf;
  float* hs = dir? hsb : hsf;
  float h = 0.f;
  for (int c=0;c<NCHK;c++){
    size_t idx = ((size_t)b*NCHK + c)*4096 + dn;
    float a = ap[idx];
    float v = hs[idx];
    hs[idx] = h;
    h = h*a + v;
  }
}

// ---------- scan phase 3: replay with prefix, emit y (both dirs) ----------
__global__ __launch_bounds__(256) void k_scan3(
    const float* __restrict__ dtf, const float* __restrict__ dtb,
    const float* __restrict__ uf, const float* __restrict__ ub,
    const float* __restrict__ bmf, const float* __restrict__ bmb,
    const float* __restrict__ cmf, const float* __restrict__ cmb,
    const float* __restrict__ alf, const float* __restrict__ alb,
    const float* __restrict__ Df, const float* __restrict__ Db,
    const float* __restrict__ z,
    const float* __restrict__ hsf, const float* __restrict__ hsb,
    float* __restrict__ yf, float* __restrict__ yb, int dir_base)
{
  int c = blockIdx.x, b = blockIdx.y;
  int dir = blockIdx.z + dir_base;
  const float* dt = dir? dtb : dtf;
  const float* u  = dir? ub  : uf;
  const float* bmp= dir? bmb : bmf;
  const float* cmp= dir? cmb : cmf;
  const float* al = dir? alb : alf;
  const float* Dv = dir? Db  : Df;
  const float* hs = dir? hsb : hsf;
  float* yout = dir? yb : yf;
  int d = threadIdx.x;
  __shared__ float sB[CHL*NS];
  __shared__ float sC[CHL*NS];
  for (int i=threadIdx.x;i<CHL*NS;i+=256){
    sB[i] = bmp[((size_t)b*SQ + c*CHL)*NS + i];
    sC[i] = cmp[((size_t)b*SQ + c*CHL)*NS + i];
  }
  float A[NS], h[NS];
  size_t o = (((size_t)b*NCHK + c)*DM + d)*NS;
  #pragma unroll
  for (int n=0;n<NS;n++){ A[n] = -__expf(al[d*NS+n]); h[n] = hs[o+n]; }
  float Dd = Dv[d];
  __syncthreads();
  for (int t=0;t<CHL;t++){
    int gt = c*CHL + t;
    size_t idx = ((size_t)b*SQ + gt)*DM + d;
    float dtv = dt[idx];
    float uv  = u[idx];
    float du  = dtv*uv;
    float y = 0.f;
    #pragma unroll
    for (int n=0;n<NS;n++){
      h[n] = h[n]*__expf(dtv*A[n]) + du*sB[t*NS+n];
      y += h[n]*sC[t*NS+n];
    }
    y += uv*Dd;
    int torig = dir ? (SQ-1-gt) : gt;
    size_t oidx = ((size_t)b*SQ + torig)*DM + d;
    float zv = z[oidx];
    yout[oidx] = y * (zv * sigm_(zv));
  }
}

// ---------- y-combine + out-LN + bf16 convert: one wave per token ----------
__global__ __launch_bounds__(256) void k_ycvt(const float* __restrict__ yf, const float* __restrict__ yb,
                                              const float* __restrict__ og, const float* __restrict__ ob,
                                              unsigned short* __restrict__ ybf){
  int tok = blockIdx.x*4 + (threadIdx.x>>6);
  int lane = threadIdx.x & 63;
  size_t base = (size_t)tok*DM;
  float4 vf = *(const float4*)(yf + base + lane*4);
  float4 vb = *(const float4*)(yb + base + lane*4);
  float4 v; v.x=0.5f*(vf.x+vb.x); v.y=0.5f*(vf.y+vb.y); v.z=0.5f*(vf.z+vb.z); v.w=0.5f*(vf.w+vb.w);
  float s = v.x+v.y+v.z+v.w;
  float ss = v.x*v.x+v.y*v.y+v.z*v.z+v.w*v.w;
  #pragma unroll
  for (int o=32;o>0;o>>=1){ s += __shfl_xor(s,o,64); ss += __shfl_xor(ss,o,64); }
  float m = s*(1.f/DM);
  float r = rsqrtf(ss*(1.f/DM)-m*m+1e-5f);
  float4 gv = *(const float4*)(og + lane*4);
  float4 bv = *(const float4*)(ob + lane*4);
  ushort4 o4;
  o4.x = f2bf((v.x-m)*r*gv.x+bv.x);
  o4.y = f2bf((v.y-m)*r*gv.y+bv.y);
  o4.z = f2bf((v.z-m)*r*gv.z+bv.z);
  o4.w = f2bf((v.w-m)*r*gv.w+bv.w);
  *(ushort4*)(ybf + base + lane*4) = o4;
}

// ---------- final via MFMA: C[8192][256] = ybf @ Woutb^T, post-LN + skip ----------
// block: 32 tokens x 256 cols, 4 waves (wave w = cols w*64..+64)
#define SOS 266
__global__ __launch_bounds__(256) void k_final_mfma(
    const unsigned short* __restrict__ ybf, const unsigned short* __restrict__ Wb,
    const float* __restrict__ pg, const float* __restrict__ pb,
    const float* __restrict__ skip, float* __restrict__ out)
{
  __shared__ float sOut[32*SOS];
  __shared__ float sm[32], sr[32];
  int tid = threadIdx.x;
  int wid = tid >> 6, lane = tid & 63;
  int lr = lane & 15, lg = lane >> 4;
  int row0 = blockIdx.x*32;
  int col0 = wid*64;
  f32x4 acc[2][4];
  #pragma unroll
  for (int m=0;m<2;m++)
    #pragma unroll
    for (int n=0;n<4;n++) acc[m][n] = (f32x4){0.f,0.f,0.f,0.f};
  #pragma unroll
  for (int k0=0;k0<DM;k0+=32){
    short8 a[2], b[4];
    #pragma unroll
    for (int m=0;m<2;m++)
      a[m] = *(const short8*)(ybf + (size_t)(row0 + m*16 + lr)*DM + k0 + lg*8);
    #pragma unroll
    for (int n=0;n<4;n++)
      b[n] = *(const short8*)(Wb + (size_t)(col0 + n*16 + lr)*DM + k0 + lg*8);
    #pragma unroll
    for (int m=0;m<2;m++)
      #pragma unroll
      for (int n=0;n<4;n++)
        acc[m][n] = __builtin_amdgcn_mfma_f32_16x16x32_bf16(a[m], b[n], acc[m][n], 0,0,0);
  }
  #pragma unroll
  for (int m=0;m<2;m++)
    #pragma unroll
    for (int n=0;n<4;n++)
      #pragma unroll
      for (int r=0;r<4;r++)
        sOut[(m*16 + lg*4 + r)*SOS + col0 + n*16 + lr] = acc[m][n][r];
  __syncthreads();
  // stats: wave wid handles rows wid*8 .. +8
  for (int j=0;j<8;j++){
    int rrow = wid*8 + j;
    const float* rp = &sOut[rrow*SOS + lane*4];
    float2 v0 = *(const float2*)(rp);
    float2 v1 = *(const float2*)(rp+2);
    float s = v0.x+v0.y+v1.x+v1.y;
    float ss = v0.x*v0.x+v0.y*v0.y+v1.x*v1.x+v1.y*v1.y;
    #pragma unroll
    for (int o=32;o>0;o>>=1){ s += __shfl_xor(s,o,64); ss += __shfl_xor(ss,o,64); }
    if (lane==0){ float m=s*(1.f/DM); sm[rrow]=m; sr[rrow]=rsqrtf(ss*(1.f/DM)-m*m+1e-5f); }
  }
  __syncthreads();
  float gv = pg[tid], bv = pb[tid];
  for (int rrow=0;rrow<32;rrow++){
    int tok = row0 + rrow;
    float v = (sOut[rrow*SOS + tid]-sm[rrow])*sr[rrow]*gv + bv + skip[(size_t)tok*DM + tid];
    out[(size_t)tok*DM + tid] = v;
  }
}

extern "C" void kernel_launch(void* const* d_in, const int* in_sizes, int n_in,
                              void* d_out, int out_size, void* d_ws, size_t ws_size,
                              hipStream_t stream)
{
  const float* input      = (const float*)d_in[0];
  const float* norm_g     = (const float*)d_in[1];
  const float* norm_b     = (const float*)d_in[2];
  const float* in_proj_w  = (const float*)d_in[3];
  const float* conv_w     = (const float*)d_in[4];
  const float* conv_b     = (const float*)d_in[5];
  const float* xproj_w    = (const float*)d_in[6];
  const float* dtproj_w   = (const float*)d_in[7];
  const float* dtproj_b   = (const float*)d_in[8];
  const float* A_log      = (const float*)d_in[9];
  const float* Dp         = (const float*)d_in[10];
  const float* conv_w_b   = (const float*)d_in[11];
  const float* conv_b_b   = (const float*)d_in[12];
  const float* xproj_w_b  = (const float*)d_in[13];
  const float* dtproj_w_b = (const float*)d_in[14];
  const float* dtproj_b_b = (const float*)d_in[15];
  const float* A_log_b    = (const float*)d_in[16];
  const float* Dp_b       = (const float*)d_in[17];
  const float* out_norm_g = (const float*)d_in[18];
  const float* out_norm_b = (const float*)d_in[19];
  const float* out_proj_w = (const float*)d_in[20];
  const float* post_norm_g= (const float*)d_in[21];
  const float* post_norm_b= (const float*)d_in[22];
  float* out = (float*)d_out;

  float* ws = (float*)d_ws;
  const size_t M2 = (size_t)NTOK*DM;           // 2,097,152 floats
  const size_t SCH = (size_t)BT*NCHK*DM*NS;    // 524,288 floats
  float* xin = ws;                 // reused as y_f
  float* z   = ws + M2;
  float* uf  = ws + 2*M2;
  float* ub  = ws + 3*M2;
  float* dtf = ws + 4*M2;
  float* dtb = ws + 5*M2;
  float* p   = ws + 6*M2;
  float* bmf = p;              p += (size_t)NTOK*NS;
  float* cmf = p;              p += (size_t)NTOK*NS;
  float* bmb = p;              p += (size_t)NTOK*NS;
  float* cmb = p;              p += (size_t)NTOK*NS;
  float* apf = p;              p += SCH;
  float* hsf = p;              p += SCH;
  float* apb = p;              p += SCH;
  float* hsb = p;              p += SCH;
  size_t base_floats = (size_t)(p - ws);
  // bf16 staging aliases:
  unsigned short* xlbf  = (unsigned short*)apf;  // 4 MB spans apf+hsf (dead before scan1)
  unsigned short* Wbf   = (unsigned short*)apb;  // 256 KB within apb (dead before scan1)
  unsigned short* ybf   = (unsigned short*)apf;  // 4 MB spans apf+hsf (after scan3, all scan ws dead)
  unsigned short* Woutb = (unsigned short*)apb;  // 128 KB within apb (apb dead after scan2)
  bool big = ws_size >= (base_floats + M2 + 1024)*sizeof(float);
  float* yf = xin;
  float* yb = big ? (ws + base_floats) : uf;

  k_lncvt<<<NTOK/4, 256, 0, stream>>>(input, norm_g, norm_b, xlbf);
  k_wcvt<<<(2*DM*DM)/1024, 256, 0, stream>>>(in_proj_w, Wbf);
  k_inproj_mfma<<<dim3(NTOK/128, 8, 1), 256, 0, stream>>>(xlbf, Wbf, xin, z);
  k_conv<<<dim3(SQ/16, BT, 2), 256, 0, stream>>>(xin, conv_w, conv_b, conv_w_b, conv_b_b, uf, ub);
  k_xproj<<<dim3(NTOK/64, 2, 1), 256, 0, stream>>>(uf, ub, xproj_w, xproj_w_b,
                                                   dtproj_w, dtproj_w_b, dtproj_b, dtproj_b_b,
                                                   dtf, dtb, bmf, cmf, bmb, cmb);
  k_scan1<<<dim3(NCHK, BT, 2), 256, 0, stream>>>(dtf, dtb, uf, ub, bmf, bmb, A_log, A_log_b,
                                                 apf, hsf, apb, hsb);
  k_scan2<<<64, 256, 0, stream>>>(apf, hsf, apb, hsb);
  // out_proj weight cvt: apb region is dead after scan2 (scan3 reads only hs)
  k_wcvt<<<(DM*DM)/1024, 256, 0, stream>>>(out_proj_w, Woutb);
  if (big){
    k_scan3<<<dim3(NCHK, BT, 2), 256, 0, stream>>>(dtf, dtb, uf, ub, bmf, bmb, cmf, cmb,
                                                   A_log, A_log_b, Dp, Dp_b, z, hsf, hsb,
                                                   yf, yb, 0);
  } else {
    k_scan3<<<dim3(NCHK, BT, 1), 256, 0, stream>>>(dtf, dtb, uf, ub, bmf, bmb, cmf, cmb,
                                                   A_log, A_log_b, Dp, Dp_b, z, hsf, hsb,
                                                   yf, yb, 0);
    k_scan3<<<dim3(NCHK, BT, 1), 256, 0, stream>>>(dtf, dtb, uf, ub, bmf, bmb, cmf, cmb,
                                                   A_log, A_log_b, Dp, Dp_b, z, hsf, hsb,
                                                   yf, yb, 1);
  }
  k_ycvt<<<NTOK/4, 256, 0, stream>>>(yf, yb, out_norm_g, out_norm_b, ybf);
  k_final_mfma<<<NTOK/32, 256, 0, stream>>>(ybf, Woutb, post_norm_g, post_norm_b, input, out);
}